// Round 11
// baseline (131.808 us; speedup 1.0000x reference)
//
#include <hip/hip_runtime.h>

#define T_LEN 3000
#define DM 1280
#define NUM_HEADS 20
#define N_CH 4
#define CHUNK 750
#define CHUNK_PAD 768
#define T_PAD 3072

typedef __bf16 bf16x8 __attribute__((ext_vector_type(8)));
typedef float f32x4 __attribute__((ext_vector_type(4)));
typedef float f32x16 __attribute__((ext_vector_type(16)));

typedef const __attribute__((address_space(1))) void* gas_p;
typedef __attribute__((address_space(3))) void* las_p;
#define GLOAD16(g, l) __builtin_amdgcn_global_load_lds((gas_p)(g), (las_p)(l), 16, 0, 0)

#define LOG2E 1.44269504088896340736f

// native RNE bf16 cast (hardware v_cvt; ~0.5 VALU op/value when paired)
__device__ __forceinline__ unsigned short f2bf(float f) {
  __bf16 b = (__bf16)f;
  union { __bf16 b; unsigned short u; } x; x.b = b;
  return x.u;
}

// ---------------- fused prep: X cvt (+pad zero), 4x W transpose, V pad zero -
#define NB_CVT (T_PAD * DM / 4 / 256)        // 3840
#define NB_TR  (40 * 40 * 4)                 // 6400
__global__ __launch_bounds__(256) void prep_kernel(
    const float* __restrict__ hs, unsigned short* __restrict__ Xb,
    const float* __restrict__ w0, const float* __restrict__ w1,
    const float* __restrict__ w2, const float* __restrict__ w3,
    unsigned short* __restrict__ Wcat, unsigned short* __restrict__ Vtb) {
  const int b = blockIdx.x;
  if (b < NB_CVT) {
    int i = b * 256 + threadIdx.x;
    ushort4 o;
    if (i < T_LEN * DM / 4) {
      const float4 v = ((const float4*)hs)[i];
      o.x = f2bf(v.x); o.y = f2bf(v.y); o.z = f2bf(v.z); o.w = f2bf(v.w);
    } else {
      o.x = 0; o.y = 0; o.z = 0; o.w = 0;
    }
    ((ushort4*)Xb)[i] = o;
    return;
  }
  if (b < NB_CVT + NB_TR) {
    const int bb = b - NB_CVT;
    const int z = bb / 1600;
    const int rem = bb - z * 1600;
    const int bx = rem % 40, by = rem / 40;
    const float* in = z == 0 ? w0 : (z == 1 ? w1 : (z == 2 ? w2 : w3));
    unsigned short* o = Wcat + (size_t)z * DM * DM;
    __shared__ float tile[32][33];
    const int x = threadIdx.x & 31, y0 = threadIdx.x >> 5;  // 32 x 8
    const int n0 = bx * 32, k0 = by * 32;
    for (int y = y0; y < 32; y += 8) tile[y][x] = in[(k0 + y) * DM + n0 + x];
    __syncthreads();
    for (int y = y0; y < 32; y += 8) o[(n0 + y) * DM + k0 + x] = f2bf(tile[x][y]);
    return;
  }
  for (int i = threadIdx.x; i < NUM_HEADS * 64 * N_CH * (CHUNK_PAD - CHUNK); i += 256) {
    int c = i % (CHUNK_PAD - CHUNK); int r = i / (CHUNK_PAD - CHUNK);
    int ch = r % N_CH; int row = r / N_CH;
    Vtb[(size_t)row * T_PAD + ch * CHUNK_PAD + CHUNK + c] = 0;
  }
}

// ---------------- fused QKV GEMM (R3-exact m97 structure) -------------------
// Q is pre-scaled by log2(e)/8 so attention can use exp2 directly.
__global__ __launch_bounds__(256) void gemm_qkv_kernel(
    const unsigned short* __restrict__ A, const unsigned short* __restrict__ Bt,
    const float* __restrict__ b0, const float* __restrict__ b1, const float* __restrict__ b2,
    unsigned short* __restrict__ dq, unsigned short* __restrict__ dk,
    unsigned short* __restrict__ dv) {
  __shared__ unsigned short As[128][64];
  __shared__ unsigned short Bs[128][64];
  const int tid = threadIdx.x;
  const int lane = tid & 63, wave = tid >> 6;
  const int h = lane >> 4, lr = lane & 15;
  const int wm = wave >> 1, wn = wave & 1;
  const int t0 = blockIdx.x * 128, n0 = blockIdx.y * 128;
  const int rs = lane >> 3;
  const int c8 = (lane & 7) ^ rs;

  const unsigned short* Ab = A + (size_t)t0 * DM + c8 * 8;
  const unsigned short* Bb = Bt + (size_t)n0 * DM + c8 * 8;

  f32x4 acc[4][4];
  const f32x4 zero4 = {0.f, 0.f, 0.f, 0.f};
#pragma unroll
  for (int i = 0; i < 4; i++)
#pragma unroll
    for (int j = 0; j < 4; j++) acc[i][j] = zero4;

  const int NT = DM / 64;  // 20
  for (int kt = 0; kt < NT; ++kt) {
    const int k0 = kt * 64;
#pragma unroll
    for (int i = 0; i < 4; ++i) {
      const int blk = wave * 4 + i;
      const size_t ro = (size_t)(blk * 8 + rs) * DM + k0;
      GLOAD16(Ab + ro, &As[blk * 8][0]);
      GLOAD16(Bb + ro, &Bs[blk * 8][0]);
    }
    __syncthreads();
#pragma unroll
    for (int kk = 0; kk < 2; ++kk) {
      bf16x8 a[4], b[4];
      const int csw = ((kk * 4 + h) ^ (lr & 7)) * 8;
#pragma unroll
      for (int mi = 0; mi < 4; mi++) a[mi] = *(const bf16x8*)&As[wm * 64 + mi * 16 + lr][csw];
#pragma unroll
      for (int ni = 0; ni < 4; ni++) b[ni] = *(const bf16x8*)&Bs[wn * 64 + ni * 16 + lr][csw];
#pragma unroll
      for (int mi = 0; mi < 4; mi++)
#pragma unroll
        for (int ni = 0; ni < 4; ni++)
          acc[mi][ni] = __builtin_amdgcn_mfma_f32_16x16x32_bf16(a[mi], b[ni], acc[mi][ni], 0, 0, 0);
    }
    __syncthreads();
  }

  const int sec = (int)blockIdx.y / 10;
  const float* bias = sec == 0 ? b0 : (sec == 1 ? b1 : b2);
  const float qs = sec == 0 ? (0.125f * LOG2E) : 1.0f;
#pragma unroll
  for (int mi = 0; mi < 4; mi++) {
#pragma unroll
    for (int j = 0; j < 4; j++) {
      int t = t0 + wm * 64 + mi * 16 + h * 4 + j;
      if (t >= T_LEN) continue;
#pragma unroll
      for (int ni = 0; ni < 4; ni++) {
        int n = n0 + wn * 64 + ni * 16 + lr;
        int nn = n - sec * DM;
        float v = (acc[mi][ni][j] + bias[nn]) * qs;
        if (sec < 2) {
          unsigned short* dst = sec == 0 ? dq : dk;
          dst[(size_t)(nn >> 6) * (T_PAD * 64) + (size_t)t * 64 + (nn & 63)] = f2bf(v);
        } else {
          int ch = t / CHUNK, s = t - ch * CHUNK;
          dv[(size_t)(nn >> 6) * (64 * T_PAD) + (size_t)(nn & 63) * T_PAD + ch * CHUNK_PAD + s] = f2bf(v);
        }
      }
    }
  }
}

// ---------------- out-proj GEMM: 128x64 m97 structure -----------------------
__global__ __launch_bounds__(256) void gemm_out_kernel(
    const unsigned short* __restrict__ A, const unsigned short* __restrict__ Bt,
    const float* __restrict__ b0, float* __restrict__ df) {
  __shared__ unsigned short As[128][64];
  __shared__ unsigned short Bs[64][64];
  const int tid = threadIdx.x;
  const int lane = tid & 63, wave = tid >> 6;
  const int h = lane >> 4, lr = lane & 15;
  const int wm = wave >> 1, wn = wave & 1;
  const int t0 = blockIdx.x * 128, n0 = blockIdx.y * 64;
  const int rs = lane >> 3;
  const int c8 = (lane & 7) ^ rs;

  const unsigned short* Ab = A + (size_t)t0 * DM + c8 * 8;
  const unsigned short* Bb = Bt + (size_t)n0 * DM + c8 * 8;

  f32x4 acc[4][2];
  const f32x4 zero4 = {0.f, 0.f, 0.f, 0.f};
#pragma unroll
  for (int i = 0; i < 4; i++)
#pragma unroll
    for (int j = 0; j < 2; j++) acc[i][j] = zero4;

  const int NT = DM / 64;
  for (int kt = 0; kt < NT; ++kt) {
    const int k0 = kt * 64;
#pragma unroll
    for (int i = 0; i < 4; ++i) {
      const int blk = wave * 4 + i;
      GLOAD16(Ab + (size_t)(blk * 8 + rs) * DM + k0, &As[blk * 8][0]);
    }
#pragma unroll
    for (int i = 0; i < 2; ++i) {
      const int blk = wave * 2 + i;
      GLOAD16(Bb + (size_t)(blk * 8 + rs) * DM + k0, &Bs[blk * 8][0]);
    }
    __syncthreads();
#pragma unroll
    for (int kk = 0; kk < 2; ++kk) {
      bf16x8 a[4], b[2];
      const int csw = ((kk * 4 + h) ^ (lr & 7)) * 8;
#pragma unroll
      for (int mi = 0; mi < 4; mi++) a[mi] = *(const bf16x8*)&As[wm * 64 + mi * 16 + lr][csw];
#pragma unroll
      for (int ni = 0; ni < 2; ni++) b[ni] = *(const bf16x8*)&Bs[wn * 32 + ni * 16 + lr][csw];
#pragma unroll
      for (int mi = 0; mi < 4; mi++)
#pragma unroll
        for (int ni = 0; ni < 2; ni++)
          acc[mi][ni] = __builtin_amdgcn_mfma_f32_16x16x32_bf16(a[mi], b[ni], acc[mi][ni], 0, 0, 0);
    }
    __syncthreads();
  }

#pragma unroll
  for (int mi = 0; mi < 4; mi++) {
#pragma unroll
    for (int j = 0; j < 4; j++) {
      int t = t0 + wm * 64 + mi * 16 + h * 4 + j;
      if (t >= T_LEN) continue;
#pragma unroll
      for (int ni = 0; ni < 2; ni++) {
        int n = n0 + wn * 32 + ni * 16 + lr;
        df[(size_t)t * DM + n] = acc[mi][ni][j] + b0[n];
      }
    }
  }
}

// ---------------- fused block-diagonal attention (32x32 MFMA) ---------------
// grid = H * N_CH * 6; 256 thr = 4 waves x 32 q-rows. No-max softmax in base-2
// (Q pre-scaled by log2e/8): P = exp2(S), row-sum deferred to epilogue.
__global__ __launch_bounds__(256) void attn_kernel(
    const unsigned short* __restrict__ Qb, const unsigned short* __restrict__ Kb,
    const unsigned short* __restrict__ Vtb, unsigned short* __restrict__ Ctx) {
  __shared__ unsigned short Ks[2][64][64];
  __shared__ unsigned short Vs[2][64][64];
  __shared__ unsigned short Ps[4][32][64];
  const int tid = threadIdx.x;
  const int lane = tid & 63, wave = tid >> 6;
  const int l31 = lane & 31, hi = lane >> 5;
  const int rs = lane >> 3;
  const int c8s = (lane & 7) ^ rs;
  int bid = blockIdx.x;
  const int qt = bid % 6; bid /= 6;
  const int ch = bid % N_CH; bid /= N_CH;
  const int hh = bid;

  const unsigned short* Qh = Qb + (size_t)hh * (T_PAD * 64);
  const unsigned short* Kh = Kb + (size_t)hh * (T_PAD * 64) + (size_t)(ch * CHUNK) * 64 + c8s * 8;
  const unsigned short* Vh = Vtb + (size_t)hh * (64 * T_PAD) + ch * CHUNK_PAD + c8s * 8;

  const int qrow0 = qt * 128 + wave * 32;
  const int tq = ch * CHUNK + qrow0 + l31;
  bf16x8 aq[4];
#pragma unroll
  for (int s = 0; s < 4; s++)
    aq[s] = *(const bf16x8*)(Qh + (size_t)tq * 64 + s * 16 + hi * 8);

  f32x16 oacc0, oacc1;
#pragma unroll
  for (int i = 0; i < 16; i++) { oacc0[i] = 0.f; oacc1[i] = 0.f; }
  float l_part[16];
#pragma unroll
  for (int i = 0; i < 16; i++) l_part[i] = 0.f;

#define A_STAGE(buf, kt) do {                                                   \
    const int s0_ = (kt) * 64;                                                  \
    _Pragma("unroll")                                                           \
    for (int i_ = 0; i_ < 2; ++i_) {                                            \
      const int blk_ = wave * 2 + i_;                                           \
      const int r_ = blk_ * 8 + rs;                                             \
      GLOAD16(Kh + (size_t)(s0_ + r_) * 64, &Ks[buf][blk_ * 8][0]);             \
      GLOAD16(Vh + (size_t)r_ * T_PAD + s0_, &Vs[buf][blk_ * 8][0]);            \
    } } while (0)

  A_STAGE(0, 0);
  __syncthreads();
  int cur = 0;
  const int xk = l31 & 7;
  for (int kt = 0; kt < 12; ++kt) {
    if (kt + 1 < 12) A_STAGE(cur ^ 1, kt + 1);

    // S = Q @ K^T (base-2 scaled)
    f32x16 s0, s1;
#pragma unroll
    for (int i = 0; i < 16; i++) { s0[i] = 0.f; s1[i] = 0.f; }
    __builtin_amdgcn_s_setprio(1);
#pragma unroll
    for (int s = 0; s < 4; s++) {
      const int cx = ((2 * s + hi) ^ xk) * 8;
      bf16x8 k0 = *(const bf16x8*)&Ks[cur][l31][cx];
      bf16x8 k1 = *(const bf16x8*)&Ks[cur][32 + l31][cx];
      s0 = __builtin_amdgcn_mfma_f32_32x32x16_bf16(aq[s], k0, s0, 0, 0, 0);
      s1 = __builtin_amdgcn_mfma_f32_32x32x16_bf16(aq[s], k1, s1, 0, 0, 0);
    }
    __builtin_amdgcn_s_setprio(0);

    // P = exp2(S); accumulate row-sum; write P to per-wave swizzled Ps
    const bool lastt = (kt == 11);
#pragma unroll
    for (int r = 0; r < 16; r++) {
      float e0 = exp2f(s0[r]);
      float e1 = exp2f(s1[r]);
      if (lastt && (l31 >= 14)) e1 = 0.f;
      l_part[r] += e0 + e1;
      const int row = (r & 3) + 8 * (r >> 2) + 4 * hi;
      const int r7 = (r & 3) + 4 * hi;
      Ps[wave][row][(((l31 >> 3) ^ r7) << 3) + (l31 & 7)] = f2bf(e0);
      Ps[wave][row][((((l31 >> 3) + 4) ^ r7) << 3) + (l31 & 7)] = f2bf(e1);
    }

    // O += P @ V
    __builtin_amdgcn_s_setprio(1);
#pragma unroll
    for (int s = 0; s < 4; s++) {
      const int cx = ((2 * s + hi) ^ xk) * 8;
      bf16x8 pa = *(const bf16x8*)&Ps[wave][l31][cx];
      bf16x8 v0 = *(const bf16x8*)&Vs[cur][l31][cx];
      bf16x8 v1 = *(const bf16x8*)&Vs[cur][32 + l31][cx];
      oacc0 = __builtin_amdgcn_mfma_f32_32x32x16_bf16(pa, v0, oacc0, 0, 0, 0);
      oacc1 = __builtin_amdgcn_mfma_f32_32x32x16_bf16(pa, v1, oacc1, 0, 0, 0);
    }
    __builtin_amdgcn_s_setprio(0);
    __syncthreads();
    cur ^= 1;
  }
#undef A_STAGE

  // deferred row-sum reduce + write
#pragma unroll
  for (int r = 0; r < 16; r++) {
    float l = l_part[r];
#pragma unroll
    for (int off = 1; off < 32; off <<= 1) l += __shfl_xor(l, off, 64);
    l_part[r] = 1.f / l;
  }
#pragma unroll
  for (int r = 0; r < 16; r++) {
    const int row = (r & 3) + 8 * (r >> 2) + 4 * hi;
    int qr = qrow0 + row;
    if (qr >= CHUNK) continue;
    int t = ch * CHUNK + qr;
    Ctx[(size_t)t * DM + hh * 64 + l31] = f2bf(oacc0[r] * l_part[r]);
    Ctx[(size_t)t * DM + hh * 64 + 32 + l31] = f2bf(oacc1[r] * l_part[r]);
  }
}

extern "C" void kernel_launch(void* const* d_in, const int* in_sizes, int n_in,
                              void* d_out, int out_size, void* d_ws, size_t ws_size,
                              hipStream_t stream) {
  const float* hs = (const float*)d_in[0];
  const float* wq = (const float*)d_in[2];
  const float* bq = (const float*)d_in[3];
  const float* wk = (const float*)d_in[4];
  const float* bk = (const float*)d_in[5];
  const float* wv = (const float*)d_in[6];
  const float* bv = (const float*)d_in[7];
  const float* wo = (const float*)d_in[8];
  const float* bo = (const float*)d_in[9];

  char* ws = (char*)d_ws;
  unsigned short* Xb = (unsigned short*)ws;   ws += (size_t)T_PAD * DM * 2;
  unsigned short* Wcat = (unsigned short*)ws; ws += (size_t)4 * DM * DM * 2;
  unsigned short* Qb = (unsigned short*)ws;   ws += (size_t)NUM_HEADS * T_PAD * 64 * 2;
  unsigned short* Kb = (unsigned short*)ws;   ws += (size_t)NUM_HEADS * T_PAD * 64 * 2;
  unsigned short* Vtb = (unsigned short*)ws;  ws += (size_t)NUM_HEADS * 64 * T_PAD * 2;
  unsigned short* Ctx = (unsigned short*)ws;  ws += (size_t)T_PAD * DM * 2;

  prep_kernel<<<NB_CVT + NB_TR + 1, 256, 0, stream>>>(hs, Xb, wq, wk, wv, wo, Wcat, Vtb);

  gemm_qkv_kernel<<<dim3(24, 30), 256, 0, stream>>>(Xb, Wcat, bq, bk, bv, Qb, Kb, Vtb);

  attn_kernel<<<NUM_HEADS * N_CH * 6, 256, 0, stream>>>(Qb, Kb, Vtb, Ctx);

  gemm_out_kernel<<<dim3(24, 20), 256, 0, stream>>>(Ctx, Wcat + (size_t)3 * DM * DM, bo, (float*)d_out);
}